// Round 1
// 2601.094 us; speedup vs baseline: 1.2178x; 1.2178x over previous
//
#include <hip/hip_runtime.h>
#include <hip/hip_bf16.h>
#include <math.h>

typedef __bf16 bf16;
typedef float  f32x4  __attribute__((ext_vector_type(4)));
typedef float  f32x16 __attribute__((ext_vector_type(16)));
typedef bf16   bf16x8 __attribute__((ext_vector_type(8)));
typedef bf16   bf16x4 __attribute__((ext_vector_type(4)));
typedef unsigned long long u64;

#define NB 64
#define NT 256
#define NS 256
#define ND 512

__device__ __forceinline__ f32x4 mfma16(bf16x8 a, bf16x8 b, f32x4 c) {
  return __builtin_amdgcn_mfma_f32_16x16x32_bf16(a, b, c, 0, 0, 0);
}
__device__ __forceinline__ f32x16 mfma32(bf16x8 a, bf16x8 b, f32x16 c) {
  return __builtin_amdgcn_mfma_f32_32x32x16_bf16(a, b, c, 0, 0, 0);
}

// ---------------- weight cast / transpose to [N][K] bf16 ----------------
__global__ void k_cast_bt(bf16* dst, int dstStride, int N, int K,
                          const float* src, int srcLd, int srcOff, int transpose) {
  int id = blockIdx.x * 256 + threadIdx.x;
  if (id >= N * K) return;
  int n = id / K, k = id % K;
  float v = transpose ? src[(size_t)k * srcLd + srcOff + n]
                      : src[(size_t)n * srcLd + srcOff + k];
  dst[(size_t)n * dstStride + k] = (bf16)v;
}

__global__ void k_init(const float* h0, bf16* h0bf, unsigned* bar) {
  int id = blockIdx.x * 256 + threadIdx.x;
  if (id < NB * ND) h0bf[id] = (bf16)h0[id];
  if (id < 1024) bar[id] = 0u;
}

// ---------------- embedding gather -> Abuf bf16 [16384][1536] ----------------
__global__ void k_embed(const int* __restrict__ nt, const int* __restrict__ pr,
                        const int* __restrict__ par, const float* __restrict__ nt_emb,
                        const float* __restrict__ rule_emb, bf16* __restrict__ Abuf) {
  int r = blockIdx.x;
  int tid = threadIdx.x;         // 128 threads
  const float* s0 = nt_emb  + (size_t)nt[r]  * 512;
  const float* s1 = rule_emb + (size_t)pr[r]  * 512;
  const float* s2 = rule_emb + (size_t)par[r] * 512;
  bf16* drow = Abuf + (size_t)r * 1536;
  for (int v = 0; v < 3; ++v) {
    int col = (tid + v * 128) * 4;
    const float* s = (col < 512) ? (s0 + col) : (col < 1024 ? s1 + col - 512 : s2 + col - 1024);
    float4 x = *(const float4*)s;
    bf16x4 y; y[0] = (bf16)x.x; y[1] = (bf16)x.y; y[2] = (bf16)x.z; y[3] = (bf16)x.w;
    *(bf16x4*)(drow + col) = y;
  }
}

// ---------------- generic bf16 MFMA GEMM: C[M,N] = concat(A0,A1,A2) @ Bt^T ----------------
__global__ __launch_bounds__(256) void k_gemm(
    const bf16* __restrict__ A0, int k0, const bf16* __restrict__ A1, int k1,
    const bf16* __restrict__ A2, int k2, const bf16* __restrict__ Bt,
    int Ktot, int N, int nbx, const float* __restrict__ bias, int act,
    float* __restrict__ Cf, bf16* __restrict__ Cbf) {
  __shared__ bf16 Al[128 * 40];
  __shared__ bf16 Bl[128 * 40];
  const int tid = threadIdx.x;
  const int bx = blockIdx.x % nbx, by = blockIdx.x / nbx;
  const int w = tid >> 6, l = tid & 63;
  const int wm = (w & 1) * 64, wn = (w >> 1) * 64;
  const int la = l & 15, kq = (l >> 4) * 8;
  const int srow = tid >> 1, skh = (tid & 1) * 16;
  const int m_g = by * 128 + srow;
  const bf16* brow = Bt + (size_t)(bx * 128 + srow) * Ktot;

  f32x4 acc[4][4];
  f32x4 z; z[0] = 0.f; z[1] = 0.f; z[2] = 0.f; z[3] = 0.f;
#pragma unroll
  for (int mt = 0; mt < 4; ++mt)
#pragma unroll
    for (int nt2 = 0; nt2 < 4; ++nt2) acc[mt][nt2] = z;

  for (int kt = 0; kt < Ktot; kt += 32) {
    __syncthreads();
    {
      int kg = kt + skh;
      const bf16* p;
      int kk = kg;
      if (kk < k0) p = A0 + (size_t)m_g * k0 + kk;
      else { kk -= k0;
        if (kk < k1) p = A1 + (size_t)m_g * k1 + kk;
        else { kk -= k1; p = A2 + (size_t)m_g * k2 + kk; } }
      *(bf16x8*)(&Al[srow * 40 + skh])     = *(const bf16x8*)p;
      *(bf16x8*)(&Al[srow * 40 + skh + 8]) = *(const bf16x8*)(p + 8);
      const bf16* q = brow + kt + skh;
      *(bf16x8*)(&Bl[srow * 40 + skh])     = *(const bf16x8*)q;
      *(bf16x8*)(&Bl[srow * 40 + skh + 8]) = *(const bf16x8*)(q + 8);
    }
    __syncthreads();
    bf16x8 af[4], bfr[4];
#pragma unroll
    for (int mt = 0; mt < 4; ++mt) af[mt]  = *(const bf16x8*)(&Al[(wm + mt * 16 + la) * 40 + kq]);
#pragma unroll
    for (int nt2 = 0; nt2 < 4; ++nt2) bfr[nt2] = *(const bf16x8*)(&Bl[(wn + nt2 * 16 + la) * 40 + kq]);
#pragma unroll
    for (int mt = 0; mt < 4; ++mt)
#pragma unroll
      for (int nt2 = 0; nt2 < 4; ++nt2)
        acc[mt][nt2] = mfma16(af[mt], bfr[nt2], acc[mt][nt2]);
  }
  const int r4 = (l >> 4) * 4, cc = l & 15;
#pragma unroll
  for (int mt = 0; mt < 4; ++mt)
#pragma unroll
    for (int nt2 = 0; nt2 < 4; ++nt2)
#pragma unroll
      for (int i = 0; i < 4; ++i) {
        int mm = by * 128 + wm + mt * 16 + r4 + i;
        int nn = bx * 128 + wn + nt2 * 16 + cc;
        float v = acc[mt][nt2][i];
        if (bias) v += bias[nn];
        if (act) v = tanhf(v);
        size_t off = (size_t)mm * N + nn;
        if (Cf)  Cf[off]  = v;
        if (Cbf) Cbf[off] = (bf16)v;
      }
}

// ---------------- persistent LSTM chain v3 ----------------
// 64 blocks x 512 threads. Block = (batch-half bg of 32 rows) x (d-slice 16 => 64 gate cols).
// Waves: w = n2 + 2*kq  (n2: which 32-col tile, kq: K-quarter 0..3).
//   kq 0,1 = h·Whh half (K 0..511), kq 2,3 = parent·Wih_par half (K 512..1023).
// W quarter in registers (wf[16], 32x32x16 B-frag). A staged once/step into LDS
// [32][1032] (pad 8 => bank stride 4, conflict-free b128). Parent half prefetched a
// step ahead and its MFMA runs DURING the global barrier spin; rows with pidx==t are
// patched from the h(t) registers (identical data) and that block defers parent MFMA
// one phase (deferred path, ~12% of steps). Flag-array barrier (64B-padded flag per
// block, wave0 polls one flag per lane + __all) - no serialized RMW fan-in.
#define LSTM_LDS 100992

__global__ __launch_bounds__(512, 2) void k_lstm_all(
    const bf16* __restrict__ gpre, const bf16* __restrict__ W2bt,
    const int* __restrict__ parent_idx, const bf16* __restrict__ h0bf,
    const float* __restrict__ c0,
    bf16* __restrict__ Hbf,      // batch-major [B*T][512] (parents + downstream)
    bf16* __restrict__ Ht,       // time-major  [T*B][512] (coalesced h broadcast)
    float* __restrict__ H, unsigned* __restrict__ flags) {
  extern __shared__ char smem[];
  bf16*  Als      = (bf16*)smem;                 // [32][1032]
  float* gls      = (float*)(smem + 66048);      // [4][32][68]
  unsigned* latew = (unsigned*)(smem + 100864);  // late-parent row mask

  const int tid = threadIdx.x;
  const int bid = blockIdx.x;
  const int bg = bid & 1, cg = bid >> 1;
  const int d0 = cg * 16;
  const int w = tid >> 6, l = tid & 63;
  const int la32 = l & 31, lhi = l >> 5, kq8 = lhi * 8;
  const int n2 = w & 1, kq = w >> 1;             // kq = K-quarter 0..3
  const int lc = n2 * 32 + la32;                 // local gate col 0..63
  const int ng = (lc >> 4) * 512 + d0 + (lc & 15);  // global gate row in W2bt

  // ---- weights: 16 K-chunks of this (col, quarter), resident in VGPRs ----
  bf16x8 wf[16];
#pragma unroll
  for (int kc = 0; kc < 16; ++kc)
    wf[kc] = *(const bf16x8*)(W2bt + (size_t)ng * 1024 + kq * 256 + kc * 16 + kq8);

  // ---- pointwise mapping (tid < 256): cells (bg*32+pb, d0+pdh .. +1) ----
  const int pb = (tid & 255) >> 3;
  const int pdh = (tid & 7) * 2;
  const int gb = bg * 32 + pb;
  // ---- parent staging mapping (tid >= 256): row pr, 64-col slice po ----
  const int ss = tid & 255, pr = ss & 31, po = ss >> 5;
  const int pgb = bg * 32 + pr;

  float creg0 = 0.f, creg1 = 0.f;
  unsigned g_pf[4];
  if (tid < 256) {
    creg0 = c0[(size_t)gb * ND + d0 + pdh];
    creg1 = c0[(size_t)gb * ND + d0 + pdh + 1];
#pragma unroll
    for (int g = 0; g < 4; ++g)
      g_pf[g] = *(const unsigned*)(gpre + ((size_t)gb * NT) * 2048 + g * 512 + d0 + pdh);
  }

  // ---- prologue: stage Ah = h0 (coalesced plain loads) ----
  if (w < 4) {
    const bf16* src = h0bf + (size_t)bg * 32 * ND;
#pragma unroll
    for (int j = 0; j < 16; ++j) {
      u64 x = *(const u64*)(src + w * 4096 + j * 256 + l * 4);
      *(u64*)(&Als[(w * 8 + (j >> 1)) * 1032 + (j & 1) * 256 + l * 4]) = x;
    }
  }
  f32x16 acc;
#pragma unroll
  for (int i = 0; i < 16; ++i) acc[i] = 0.f;
  bool deferred = false;
  __syncthreads();

  for (int t = 0; t < NT; ++t) {
    u64 preg[16];
    // ---- phase 1: h-waves MFMA; parent-waves: deferred MFMA + issue t+1 loads ----
    if (w < 4) {
#pragma unroll
      for (int kc = 0; kc < 16; ++kc) {
        bf16x8 a = *(const bf16x8*)(&Als[la32 * 1032 + kq * 256 + kc * 16 + kq8]);
        acc = mfma32(a, wf[kc], acc);
      }
    } else {
      if (deferred) {
#pragma unroll
        for (int kc = 0; kc < 16; ++kc) {
          bf16x8 a = *(const bf16x8*)(&Als[la32 * 1032 + kq * 256 + kc * 16 + kq8]);
          acc = mfma32(a, wf[kc], acc);
        }
      }
      if (t + 1 < NT) {
        int pv = parent_idx[(size_t)pgb * NT + t + 1];
        if (pv < t) {                      // prefetchable parent (visible history)
          const bf16* p = Hbf + ((size_t)pgb * NT + pv) * ND + po * 64;
#pragma unroll
          for (int j = 0; j < 16; ++j)
            preg[j] = __hip_atomic_load((const u64*)(p + j * 4),
                                        __ATOMIC_RELAXED, __HIP_MEMORY_SCOPE_AGENT);
        } else {                           // pidx==t handled post-barrier; >t stays 0
#pragma unroll
          for (int j = 0; j < 16; ++j) preg[j] = 0ull;
        }
      }
    }
    // ---- write K-quarter partials to gls ----
#pragma unroll
    for (int i = 0; i < 16; ++i) {
      int row = (i & 3) + 8 * (i >> 2) + 4 * lhi;   // verified 32x32 C/D mapping
      gls[(kq * 32 + row) * 68 + lc] = acc[i];
    }
#pragma unroll
    for (int i = 0; i < 16; ++i) acc[i] = 0.f;
    __syncthreads();  // S_a

    // ---- pointwise: sum 4 quarters + gpre, gates, cell update, h stores ----
    if (tid < 256) {
      union { unsigned u; bf16 h[2]; } gv[4];
#pragma unroll
      for (int g = 0; g < 4; ++g) gv[g].u = g_pf[g];
      float hn[2];
#pragma unroll
      for (int j = 0; j < 2; ++j) {
        float s[4];
#pragma unroll
        for (int g = 0; g < 4; ++g) {
          float v = 0.f;
#pragma unroll
          for (int q = 0; q < 4; ++q) v += gls[(q * 32 + pb) * 68 + g * 16 + pdh + j];
          s[g] = v + (float)gv[g].h[j];
        }
        float si = 1.f / (1.f + __expf(-s[0]));
        float sf = 1.f / (1.f + __expf(-s[1]));
        float so = 1.f / (1.f + __expf(-s[3]));
        float e2 = __expf(2.f * fminf(fmaxf(s[2], -15.f), 15.f));
        float tg = (e2 - 1.f) / (e2 + 1.f);
        float cp = j ? creg1 : creg0;
        float cn = sf * cp + si * tg;
        float e2c = __expf(2.f * fminf(fmaxf(cn, -15.f), 15.f));
        float tc = (e2c - 1.f) / (e2c + 1.f);
        if (j) creg1 = cn; else creg0 = cn;
        hn[j] = so * tc;
      }
      union { unsigned u; bf16 h[2]; } pk;
      pk.h[0] = (bf16)hn[0]; pk.h[1] = (bf16)hn[1];
      size_t hb = ((size_t)gb * NT + t) * ND + d0 + pdh;
      size_t ho = ((size_t)t * NB + gb) * ND + d0 + pdh;
      __hip_atomic_store((unsigned*)(Hbf + hb), pk.u, __ATOMIC_RELAXED, __HIP_MEMORY_SCOPE_AGENT);
      __hip_atomic_store((unsigned*)(Ht + ho), pk.u, __ATOMIC_RELAXED, __HIP_MEMORY_SCOPE_AGENT);
      *(float2*)(H + hb) = make_float2(hn[0], hn[1]);
      if (t + 1 < NT) {
#pragma unroll
        for (int g = 0; g < 4; ++g)
          g_pf[g] = *(const unsigned*)(gpre + ((size_t)gb * NT + t + 1) * 2048 + g * 512 + d0 + pdh);
      }
    }

    // ---- stage Ap(t+1) + late-parent mask ----
    bool deferred_next = false;
    if (w >= 4 && t + 1 < NT) {
#pragma unroll
      for (int j = 0; j < 16; ++j)
        *(u64*)(&Als[pr * 1032 + 512 + po * 64 + j * 4]) = preg[j];
      int pv2 = parent_idx[(size_t)(bg * 32 + la32) * NT + t + 1];
      unsigned mask = (unsigned)__ballot(pv2 == t);
      if (tid == 256) *latew = mask;
      deferred_next = (mask != 0u);
    }
    if (t + 1 == NT) break;
    __syncthreads();  // S_b: gls consumed, Ap staged, h stores drained

    // ---- global barrier (flag array); parent MFMA hides under the spin ----
    if (w == 0) {
      if (l == 0)
        __hip_atomic_store(flags + bid * 16, (unsigned)(t + 1),
                           __ATOMIC_RELAXED, __HIP_MEMORY_SCOPE_AGENT);
      const unsigned tgt = (unsigned)(t + 1);
      const unsigned* fp = flags + l * 16;
      while (!__all((int)(__hip_atomic_load(fp, __ATOMIC_RELAXED,
                                            __HIP_MEMORY_SCOPE_AGENT) >= tgt)))
        __builtin_amdgcn_s_sleep(1);
    } else if (w >= 4 && !deferred_next) {
#pragma unroll
      for (int kc = 0; kc < 16; ++kc) {
        bf16x8 a = *(const bf16x8*)(&Als[la32 * 1032 + kq * 256 + kc * 16 + kq8]);
        acc = mfma32(a, wf[kc], acc);
      }
    }
    __syncthreads();  // S_c: h(t) globally visible

    // ---- stage Ah = h(t) (coalesced), patch late parents from same registers ----
    if (w < 4) {
      unsigned lmask = *latew;
      const bf16* src = Ht + ((size_t)t * NB + bg * 32) * ND;
      u64 hreg[16];
#pragma unroll
      for (int j = 0; j < 16; ++j)
        hreg[j] = __hip_atomic_load((const u64*)(src + w * 4096 + j * 256 + l * 4),
                                    __ATOMIC_RELAXED, __HIP_MEMORY_SCOPE_AGENT);
#pragma unroll
      for (int j = 0; j < 16; ++j) {
        const int row = w * 8 + (j >> 1), col = (j & 1) * 256 + l * 4;
        *(u64*)(&Als[row * 1032 + col]) = hreg[j];
        if ((lmask >> row) & 1u)
          *(u64*)(&Als[row * 1032 + 512 + col]) = hreg[j];
      }
    }
    __syncthreads();  // S_d
    deferred = deferred_next;
  }
}

// ---------------- fp32 GEMM: C[M,N] = A[M,K] @ B[K,N] (normal B) ----------------
__global__ __launch_bounds__(256) void k_gemm_f32(
    const float* __restrict__ A, const float* __restrict__ Bm, float* __restrict__ C,
    int M, int N, int K, int nbx) {
  __shared__ float At[16 * 68];
  __shared__ float Bs[16 * 68];
  const int tid = threadIdx.x;
  const int bx = blockIdx.x % nbx, by = blockIdx.x / nbx;
  const int ty = tid >> 4, tx = tid & 15;
  const int am = tid >> 2, ak = (tid & 3) * 4;
  const int bk = tid >> 4, bn = (tid & 15) * 4;
  float acc[4][4] = {};
  for (int kb = 0; kb < K; kb += 16) {
    __syncthreads();
    float4 a4 = *(const float4*)(A + (size_t)(by * 64 + am) * K + kb + ak);
    At[(ak + 0) * 68 + am] = a4.x; At[(ak + 1) * 68 + am] = a4.y;
    At[(ak + 2) * 68 + am] = a4.z; At[(ak + 3) * 68 + am] = a4.w;
    *(float4*)(&Bs[bk * 68 + bn]) = *(const float4*)(Bm + (size_t)(kb + bk) * N + bx * 64 + bn);
    __syncthreads();
#pragma unroll
    for (int kk = 0; kk < 16; ++kk) {
      float4 av = *(const float4*)(&At[kk * 68 + ty * 4]);
      float4 bv = *(const float4*)(&Bs[kk * 68 + tx * 4]);
      float aa[4] = {av.x, av.y, av.z, av.w};
      float bb[4] = {bv.x, bv.y, bv.z, bv.w};
#pragma unroll
      for (int i = 0; i < 4; ++i)
#pragma unroll
        for (int j = 0; j < 4; ++j) acc[i][j] += aa[i] * bb[j];
    }
  }
#pragma unroll
  for (int i = 0; i < 4; ++i) {
    float4 o; o.x = acc[i][0]; o.y = acc[i][1]; o.z = acc[i][2]; o.w = acc[i][3];
    *(float4*)(C + (size_t)(by * 64 + ty * 4 + i) * N + bx * 64 + tx * 4) = o;
  }
}

// ---------------- fused attention: scores (fp32) + softmax + context ----------------
__global__ __launch_bounds__(256) void k_attn(
    const float* __restrict__ Q, const float* __restrict__ ctx, bf16* __restrict__ Cbf,
    float* __restrict__ prob0, float* __restrict__ prob1) {
  __shared__ float Sl[64 * 257];
  __shared__ float T1[16 * 68];
  __shared__ float T2[16 * 68];
  const int tid = threadIdx.x;
  const int b = blockIdx.x >> 2, ch = blockIdx.x & 3;
  const int t0 = ch * 64;
  const int row0 = b * NT + t0;
  const int ty = tid >> 4, tx = tid & 15;
  const int sl_r = tid >> 2, sl_k = (tid & 3) * 4;

  for (int sc = 0; sc < 4; ++sc) {
    float acc[4][4] = {};
    for (int kc = 0; kc < 512; kc += 16) {
      __syncthreads();
      float4 q4 = *(const float4*)(Q + (size_t)(row0 + sl_r) * ND + kc + sl_k);
      T1[(sl_k + 0) * 68 + sl_r] = q4.x; T1[(sl_k + 1) * 68 + sl_r] = q4.y;
      T1[(sl_k + 2) * 68 + sl_r] = q4.z; T1[(sl_k + 3) * 68 + sl_r] = q4.w;
      float4 c4 = *(const float4*)(ctx + (size_t)(b * NS + sc * 64 + sl_r) * ND + kc + sl_k);
      T2[(sl_k + 0) * 68 + sl_r] = c4.x; T2[(sl_k + 1) * 68 + sl_r] = c4.y;
      T2[(sl_k + 2) * 68 + sl_r] = c4.z; T2[(sl_k + 3) * 68 + sl_r] = c4.w;
      __syncthreads();
#pragma unroll
      for (int kk = 0; kk < 16; ++kk) {
        float4 qv = *(const float4*)(&T1[kk * 68 + ty * 4]);
        float4 cv = *(const float4*)(&T2[kk * 68 + tx * 4]);
        float qa[4] = {qv.x, qv.y, qv.z, qv.w};
        float ca[4] = {cv.x, cv.y, cv.z, cv.w};
#pragma unroll
        for (int i = 0; i < 4; ++i)
#pragma unroll
          for (int j = 0; j < 4; ++j) acc[i][j] += qa[i] * ca[j];
      }
    }
#pragma unroll
    for (int i = 0; i < 4; ++i)
#pragma unroll
      for (int j = 0; j < 4; ++j)
        Sl[(ty * 4 + i) * 257 + sc * 64 + tx * 4 + j] = acc[i][j];
  }
  __syncthreads();

  if (tid < 64) {
    float* row = &Sl[tid * 257];
    float mx = -1e30f;
    for (int s = 0; s < 256; ++s) mx = fmaxf(mx, row[s]);
    float sum = 0.f;
    for (int s = 0; s < 256; ++s) { float e = __expf(row[s] - mx); row[s] = e; sum += e; }
    float inv = 1.f / sum;
    for (int s = 0; s < 256; ++s) row[s] *= inv;
  }
  __syncthreads();
  if (prob0) {
    int pr = tid >> 2, pq = (tid & 3) * 64;
    size_t po = (size_t)(row0 + pr) * NS + pq;
    for (int s = 0; s < 64; s += 4) {
      float4 o; o.x = Sl[pr * 257 + pq + s];     o.y = Sl[pr * 257 + pq + s + 1];
      o.z = Sl[pr * 257 + pq + s + 2];           o.w = Sl[pr * 257 + pq + s + 3];
      *(float4*)(prob0 + po + s) = o;
      *(float4*)(prob1 + po + s) = o;
    }
  }

  const int c_sr = tid >> 4, c_n4 = (tid & 15) * 4;
  for (int dc = 0; dc < 512; dc += 64) {
    float acc[4][4] = {};
    for (int s0c = 0; s0c < 256; s0c += 16) {
      __syncthreads();
      *(float4*)(&T2[c_sr * 68 + c_n4]) =
          *(const float4*)(ctx + (size_t)(b * NS + s0c + c_sr) * ND + dc + c_n4);
      __syncthreads();
#pragma unroll
      for (int kk = 0; kk < 16; ++kk) {
        float p0 = Sl[(ty * 4 + 0) * 257 + s0c + kk];
        float p1 = Sl[(ty * 4 + 1) * 257 + s0c + kk];
        float p2 = Sl[(ty * 4 + 2) * 257 + s0c + kk];
        float p3 = Sl[(ty * 4 + 3) * 257 + s0c + kk];
        float4 cv = *(const float4*)(&T2[kk * 68 + tx * 4]);
        float ca[4] = {cv.x, cv.y, cv.z, cv.w};
#pragma unroll
        for (int j = 0; j < 4; ++j) {
          acc[0][j] += p0 * ca[j]; acc[1][j] += p1 * ca[j];
          acc[2][j] += p2 * ca[j]; acc[3][j] += p3 * ca[j];
        }
      }
    }
#pragma unroll
    for (int i = 0; i < 4; ++i)
#pragma unroll
      for (int j = 0; j < 4; ++j)
        Cbf[(size_t)(row0 + ty * 4 + i) * ND + dc + tx * 4 + j] = (bf16)acc[i][j];
  }
}

// ---------------- host ----------------
extern "C" void kernel_launch(void* const* d_in, const int* in_sizes, int n_in,
                              void* d_out, int out_size, void* d_ws, size_t ws_size,
                              hipStream_t stream) {
  const int*   nt       = (const int*)d_in[0];
  const int*   prules   = (const int*)d_in[1];
  const int*   parules  = (const int*)d_in[2];
  const int*   pidx     = (const int*)d_in[3];
  const float* src_ctx  = (const float*)d_in[4];
  const float* rest_ctx = (const float*)d_in[5];
  const float* h0       = (const float*)d_in[8];
  const float* c0       = (const float*)d_in[9];
  const float* nt_emb   = (const float*)d_in[10];
  const float* rule_emb = (const float*)d_in[11];
  const float* Wih      = (const float*)d_in[12];
  const float* Whh      = (const float*)d_in[13];
  const float* b_lstm   = (const float*)d_in[14];
  const float* Wa_src   = (const float*)d_in[15];
  const float* Wo_src   = (const float*)d_in[16];
  const float* Wa_var   = (const float*)d_in[17];
  const float* Wo_var   = (const float*)d_in[18];
  const float* Wl       = (const float*)d_in[19];
  const float* bl       = (const float*)d_in[20];
  float* out = (float*)d_out;

  char* p = (char*)d_ws;
  bf16*  Abuf    = (bf16*)p;  p += 50331648;   // [16384][1536]
  bf16*  gpre    = (bf16*)p;  p += 67108864;   // [16384][2048]
  float* H       = (float*)p; p += 33554432;   // [16384][512]
  bf16*  Hbf     = (bf16*)p;  p += 16777216;
  float* SRCOUT  = (float*)p; p += 33554432;
  bf16*  SRCOUTb = (bf16*)p;  p += 16777216;
  bf16*  Wemb_bt = (bf16*)p;  p += 6291456;    // [2048][1536]
  bf16*  W2bt    = (bf16*)p;  p += 4194304;    // [2048][1024] = [Whh | Wih_par]
  bf16*  Wos_bt  = (bf16*)p;  p += 1048576;
  bf16*  Wov_bt  = (bf16*)p;  p += 1048576;
  bf16*  Wl_bt   = (bf16*)p;  p += 1572864;
  bf16*  h0bf    = (bf16*)p;  p += 65536;
  unsigned* bar  = (unsigned*)p; p += 4096;    // 64 flags, 64B-padded
  // Ht (time-major h mirror, LSTM-internal) aliases Abuf: Abuf is dead after the
  // gpre GEMM, and Q1 (same region) is only written after the LSTM completes.
  bf16*  Ht    = (bf16*)Abuf;                  // [256*64][512] = 16 MB
  float* Q1    = (float*)Abuf;
  bf16*  C1bf  = (bf16*)((char*)Abuf + 33554432);
  float* Q2    = (float*)gpre;
  bf16*  C2bf  = (bf16*)((char*)gpre + 33554432);
  bf16*  VARbf = (bf16*)((char*)gpre + 50331648);
  float* out_p0 = out + 8388608;
  float* out_p1 = out + 12582912;

  hipFuncSetAttribute(reinterpret_cast<const void*>(k_lstm_all),
                      hipFuncAttributeMaxDynamicSharedMemorySize, LSTM_LDS);

  k_cast_bt<<<(2048*1536+255)/256, 256, 0, stream>>>(Wemb_bt, 1536, 2048, 1536, Wih, 2048, 0, 0);
  k_cast_bt<<<(2048*512 +255)/256, 256, 0, stream>>>(W2bt,        1024, 2048, 512, Whh, 512, 0, 0);
  k_cast_bt<<<(2048*512 +255)/256, 256, 0, stream>>>(W2bt + 512,  1024, 2048, 512, Wih, 2048, 1536, 0);
  k_cast_bt<<<(512*1024 +255)/256, 256, 0, stream>>>(Wos_bt, 1024, 512, 1024, Wo_src, 512, 0, 1);
  k_cast_bt<<<(512*1024 +255)/256, 256, 0, stream>>>(Wov_bt, 1024, 512, 1024, Wo_var, 512, 0, 1);
  k_cast_bt<<<(512*1536 +255)/256, 256, 0, stream>>>(Wl_bt,  1536, 512, 1536, Wl, 512, 0, 1);
  k_init<<<128, 256, 0, stream>>>(h0, h0bf, bar);
  k_embed<<<16384, 128, 0, stream>>>(nt, prules, parules, nt_emb, rule_emb, Abuf);

  k_gemm<<<2048, 256, 0, stream>>>(Abuf, 1536, nullptr, 0, nullptr, 0,
                                   Wemb_bt, 1536, 2048, 16, b_lstm, 0, nullptr, gpre);

  k_lstm_all<<<64, 512, LSTM_LDS, stream>>>(gpre, W2bt, pidx, h0bf, c0, Hbf, Ht, H, bar);

  k_gemm_f32<<<2048, 256, 0, stream>>>(H, Wa_src, Q1, 16384, 512, 512, 8);
  k_attn<<<256, 256, 0, stream>>>(Q1, src_ctx, C1bf, nullptr, nullptr);
  k_gemm<<<512, 256, 0, stream>>>(C1bf, 512, Hbf, 512, nullptr, 0,
                                  Wos_bt, 1024, 512, 4, nullptr, 1, SRCOUT, SRCOUTb);
  k_gemm_f32<<<2048, 256, 0, stream>>>(SRCOUT, Wa_var, Q2, 16384, 512, 512, 8);
  k_attn<<<256, 256, 0, stream>>>(Q2, rest_ctx, C2bf, out_p0, out_p1);
  k_gemm<<<512, 256, 0, stream>>>(C2bf, 512, SRCOUTb, 512, nullptr, 0,
                                  Wov_bt, 1024, 512, 4, nullptr, 1, nullptr, VARbf);
  k_gemm<<<512, 256, 0, stream>>>(Hbf, 512, SRCOUTb, 512, VARbf, 512,
                                  Wl_bt, 1536, 512, 4, bl, 1, out, nullptr);
}